// Round 11
// baseline (190.560 us; speedup 1.0000x reference)
//
#include <hip/hip_runtime.h>
#include <hip/hip_bf16.h>
#include <math.h>

#define B_  4
#define S_  2048
#define D_  512
#define H_  8
#define DK_ 64
#define M_  (B_ * S_)   // 8192

using bf16   = __bf16;
using bf16x4 = __bf16 __attribute__((ext_vector_type(4)));
using bf16x8 = __bf16 __attribute__((ext_vector_type(8)));
using f32x4  = float __attribute__((ext_vector_type(4)));

#define MFMA16(a, b, c) __builtin_amdgcn_mfma_f32_16x16x32_bf16((a), (b), (c), 0, 0, 0)
#define EXP2(x) exp2f(x)

typedef __attribute__((address_space(3))) void       lds_void;
typedef const __attribute__((address_space(1))) void gbl_void;

__device__ __forceinline__ void async16(const bf16* g, bf16* lds) {
    __builtin_amdgcn_global_load_lds((gbl_void*)g, (lds_void*)lds, 16, 0, 0);
}

__device__ __forceinline__ bf16x8 ldg8(const bf16* p) {
    return *reinterpret_cast<const bf16x8*>(p);
}

// Fragment-major layout for a [R x 512] matrix (rows = MFMA m/n dim, cols = K):
// chunk(g,k0,kk,t) holds rows g*64+t*16+{0..15}, cols k0*64+kk*32+{0..31};
// lane = (k_sub>>3)*16 + (row&15), 8 bf16 per lane.
__device__ __forceinline__ size_t fragbase(int g, int k0, int kk, int t) {
    return ((((size_t)(g * 8 + k0) * 2 + kk) * 4 + t) * 64) * 8;
}

// ---------------------------------------------------------------------------
// Fused f32->bf16 conversion + fragment-major re-layout (r5-proven form).
// ---------------------------------------------------------------------------
__global__ __launch_bounds__(256) void cvt_all(
    const float* __restrict__ x0, const float* __restrict__ x1, const float* __restrict__ x2,
    const float* __restrict__ w0, const float* __restrict__ w1,
    const float* __restrict__ w2, const float* __restrict__ w3,
    bf16* __restrict__ dst)
{
    const int w    = blockIdx.x * 4 + (threadIdx.x >> 6);  // wave id, 0..26623
    const int lane = threadIdx.x & 63;
    const int lg = lane >> 4, lc = lane & 15;
    const float* src;
    int c;
    size_t dbase;
    if (w < 24576) {                                       // X tensors: 3 x 8192 chunks
        const int seg = w >> 13;
        c = w & 8191;
        src = (seg == 0) ? x0 : (seg == 1) ? x1 : x2;
        dbase = (size_t)seg << 22;
    } else {                                               // W tensors: 4 x 512 chunks
        const int jj = w - 24576;
        const int seg = jj >> 9;
        c = jj & 511;
        src = (seg == 0) ? w0 : (seg == 1) ? w1 : (seg == 2) ? w2 : w3;
        dbase = ((size_t)3 << 22) + ((size_t)seg << 18);
    }
    const int g = c >> 6, k0 = (c >> 3) & 7, kk = (c >> 2) & 1, t = c & 3;
    const size_t soff = ((size_t)(g * 64 + t * 16 + lc) << 9) + k0 * 64 + kk * 32 + lg * 8;
    f32x4 a = *reinterpret_cast<const f32x4*>(src + soff);
    f32x4 b = *reinterpret_cast<const f32x4*>(src + soff + 4);
    bf16x8 r;
    #pragma unroll
    for (int j = 0; j < 4; ++j) { r[j] = (bf16)a[j]; r[j + 4] = (bf16)b[j]; }
    *reinterpret_cast<bf16x8*>(dst + dbase + ((size_t)c << 9) + (size_t)lane * 8) = r;
}

// ---------------------------------------------------------------------------
// QKV projection, LDS-FREE (r5-proven form). Grid 768; XCD-affine mt decode.
// ---------------------------------------------------------------------------
__global__ __launch_bounds__(256) void gemm_qkv(
    const bf16* __restrict__ Xf, const bf16* __restrict__ Wf,
    bf16* __restrict__ qkv)
{
    const int bx  = blockIdx.x;
    const int xcd = bx & 7;
    const int idx = bx >> 3;
    const int mt  = xcd + 8 * (idx & 7);       // 0..63: X 128-row tile
    const int rest = idx >> 3;
    const int nt  = rest & 3;                  // 0..3: W 128-row tile
    const int z   = rest >> 2;                 // 0..2

    const bf16* Xz = Xf + (size_t)z * M_ * D_;
    const bf16* Wz = Wf + (size_t)z * D_ * D_;
    const bool vz = (z == 2);
    const bf16* A  = vz ? Xz : Wz;
    const bf16* Bm = vz ? Wz : Xz;

    const int lane = threadIdx.x & 63;
    const int wave = threadIdx.x >> 6;
    const int lc = lane & 15;
    const int lg = lane >> 4;
    const int gA = (vz ? 2 * mt : 2 * nt) + (wave >> 1);
    const int gB = (vz ? 2 * nt : 2 * mt) + (wave & 1);

    f32x4 acc[4][4] = {};

    #pragma unroll
    for (int k0 = 0; k0 < 8; ++k0) {
        #pragma unroll
        for (int kk = 0; kk < 2; ++kk) {
            bf16x8 af[4], bfm[4];
            #pragma unroll
            for (int t = 0; t < 4; ++t)
                af[t] = ldg8(A + fragbase(gA, k0, kk, t) + (size_t)lane * 8);
            #pragma unroll
            for (int t = 0; t < 4; ++t)
                bfm[t] = ldg8(Bm + fragbase(gB, k0, kk, t) + (size_t)lane * 8);
            #pragma unroll
            for (int mi = 0; mi < 4; ++mi)
                #pragma unroll
                for (int ni = 0; ni < 4; ++ni)
                    acc[mi][ni] = MFMA16(af[mi], bfm[ni], acc[mi][ni]);
        }
    }

    if (z < 2) {
        bf16* Y = qkv + (size_t)z * M_ * D_;
        const float sc = (z == 0) ? 0.125f * 1.4426950408889634f : 1.0f;
        #pragma unroll
        for (int mi = 0; mi < 4; ++mi)
            #pragma unroll
            for (int ni = 0; ni < 4; ++ni) {
                const int d = gA * 64 + mi * 16 + lg * 4;
                const int s = gB * 64 + ni * 16 + lc;
                bf16x4 v;
                #pragma unroll
                for (int r = 0; r < 4; ++r) v[r] = (bf16)(acc[mi][ni][r] * sc);
                const size_t oidx =
                    ((((size_t)(s >> 11) * H_ + (d >> 6)) * S_
                      + (s & (S_ - 1))) << 6) + (d & 63);
                *reinterpret_cast<bf16x4*>(&Y[oidx]) = v;
            }
    } else {
        bf16* Y = qkv + (size_t)2 * M_ * D_;
        #pragma unroll
        for (int mi = 0; mi < 4; ++mi)
            #pragma unroll
            for (int ni = 0; ni < 4; ++ni) {
                const int s = gA * 64 + mi * 16 + lg * 4;
                const int d = gB * 64 + ni * 16 + lc;
                bf16x4 v;
                #pragma unroll
                for (int r = 0; r < 4; ++r) v[r] = (bf16)acc[mi][ni][r];
                const size_t oidx =
                    ((((size_t)(s >> 11)) * H_ + (d >> 6)) << 17)
                    + (size_t)(d & 63) * S_ + (s & (S_ - 1));
                *reinterpret_cast<bf16x4*>(&Y[oidx]) = v;
            }
    }
}

// ---------------------------------------------------------------------------
// Output projection, LDS-free (r5-proven form). Grid 512, XCD swizzle.
// ---------------------------------------------------------------------------
__global__ __launch_bounds__(256) void gemm_out(
    const bf16* __restrict__ CtxF, const bf16* __restrict__ WoF,
    float* __restrict__ out)
{
    const int bx  = blockIdx.x;
    const int xcd = bx & 7;
    const int idx = bx >> 3;
    const int mt  = xcd + 8 * (idx & 15);      // 0..127: ctx 64-row s-group
    const int nt  = idx >> 4;                  // 0..3: Wo 128-row d-tile

    const int lane = threadIdx.x & 63;
    const int wave = threadIdx.x >> 6;
    const int lc = lane & 15;
    const int lg = lane >> 4;
    const int gA = 2 * nt + (wave >> 1);       // Wo 64-row group
    const int tA = (wave & 1) * 2;             // 2 d-tiles per wave
    const int gB = mt;                         // ctx s-group

    f32x4 acc[2][4] = {};

    #pragma unroll
    for (int k0 = 0; k0 < 8; ++k0) {
        #pragma unroll
        for (int kk = 0; kk < 2; ++kk) {
            bf16x8 af[2], bfm[4];
            #pragma unroll
            for (int ai = 0; ai < 2; ++ai)
                af[ai] = ldg8(WoF + fragbase(gA, k0, kk, tA + ai) + (size_t)lane * 8);
            #pragma unroll
            for (int t = 0; t < 4; ++t)
                bfm[t] = ldg8(CtxF + fragbase(gB, k0, kk, t) + (size_t)lane * 8);
            #pragma unroll
            for (int ai = 0; ai < 2; ++ai)
                #pragma unroll
                for (int ni = 0; ni < 4; ++ni)
                    acc[ai][ni] = MFMA16(af[ai], bfm[ni], acc[ai][ni]);
        }
    }

    #pragma unroll
    for (int ai = 0; ai < 2; ++ai)
        #pragma unroll
        for (int ni = 0; ni < 4; ++ni) {
            const int d = gA * 64 + (tA + ai) * 16 + lg * 4;
            const int s = gB * 64 + ni * 16 + lc;
            *reinterpret_cast<f32x4*>(&out[(size_t)s * D_ + d]) = acc[ai][ni];
        }
}

// ---------------------------------------------------------------------------
// P->B-fragment in registers (permlane16_swap builtin; sigma-permuted V).
// ---------------------------------------------------------------------------
__device__ __forceinline__ bf16x8 pfrag(const f32x4 a, const f32x4 b) {
    union U4 { bf16x4 v; unsigned int u[2]; };
    U4 pa, pb;
    #pragma unroll
    for (int r = 0; r < 4; ++r) { pa.v[r] = (bf16)a[r]; pb.v[r] = (bf16)b[r]; }
    auto r0 = __builtin_amdgcn_permlane16_swap(pa.u[0], pb.u[0], false, false);
    auto r1 = __builtin_amdgcn_permlane16_swap(pa.u[1], pb.u[1], false, false);
    union U8 { unsigned int u[4]; bf16x8 v; } out;
    out.u[0] = r0[0]; out.u[1] = r1[0]; out.u[2] = r0[1]; out.u[3] = r1[1];
    return out.v;
}

// ---------------------------------------------------------------------------
// Causal flash attention, K-SPLIT + 1-ROUND GRID (r11). Model from r5/r10:
// T = crit_iters x (~2k fixed + LDS-read component). r10 proved k-split cuts
// per-iter 3.07k->2.56k but its 1024-block grid ran 2 rounds (48 crit iters).
// Now: r5's anti-diagonal PAIRING (512 blocks, single round, 32 crit iters)
// with 16-WAVE blocks (1024 thr): wave = {hi,lo} x 4 q-row-groups x 2 k-halves.
// Per wave per tile: 8 ds_read_b128 + 8 MFMA + 8 exp2 (r10's proven compute).
// Staging: 1 async16/wave/tile (piece = wave&7; identical LDS image to r5).
// Ring-4 KV (64 KB), counted vmcnt(2)/(1)/(0). k-half merge ONCE at the end
// via LDS scratch. 2 blocks/CU = 32 waves/CU requires VGPR<=64 — r10's
// k-split body measured 52 VGPR, so __launch_bounds__(1024,8) holds.
// ---------------------------------------------------------------------------
__global__ __launch_bounds__(1024, 8) void attn(
    const bf16* __restrict__ QKV, bf16* __restrict__ CtxF)
{
    const int bx = blockIdx.x;
    const int bh = (bx & 7) * 4 + ((bx >> 3) & 3);   // same-XCD bh grouping
    const int pi = bx >> 5;                           // 0..15
    const int b = bh >> 3, h = bh & 7;
    const size_t plane = (size_t)S_ * DK_;
    const bf16* Q  = QKV + (size_t)bh * plane;
    const bf16* Kp = QKV + (size_t)(B_ * H_) * plane + (size_t)bh * plane;
    const bf16* Vt = QKV + 2 * (size_t)(B_ * H_) * plane + (size_t)bh * plane;

    const int lane = threadIdx.x & 63;
    const int wave = threadIdx.x >> 6;   // 0..15
    const int half = wave >> 3;          // 0 -> hi tile, 1 -> lo tile
    const int w7   = wave & 7;           // staging piece / (wv,kh) code
    const int wv   = w7 >> 1;            // q row-group 0..3
    const int kh   = w7 & 1;             // k-half
    const int lc = lane & 15;
    const int lg = lane >> 4;
    const int sg = ((lg & 1) << 1) | (lg >> 1);      // sigma(lg): swap 1<->2
    const int mrow = wv * 16 + lc;       // q row within tile for this lane

    // [ring][K/V][64x64 tile]: contiguous 64 KB so tail phases can alias it
    __shared__ bf16 KV[4][2][64 * 64];

    const int lo = pi;
    const int hi = 31 - pi;              // hi >= 16 always
    const int myq = half ? lo : hi;      // this wave's q-tile

    const int qR = myq * 64 + mrow;
    bf16x8 qf0 = ldg8(Q + (size_t)qR * DK_ + lg * 8);
    bf16x8 qf1 = ldg8(Q + (size_t)qR * DK_ + 32 + lg * 8);

    f32x4 accO[4] = {};
    float li = 0.f;

    // Staging: 1 async16 per wave per tile. half==0 waves stage K piece w7,
    // half==1 waves stage V piece w7. Piece p: dst (p*64+lane)*8, src rows
    // (p&3)*16+lc, dk/s-chunk (p>>2)*4 + lg (K) or + sigma(lg) (V) — the
    // byte-identical LDS image to r5/r10's 2-per-wave scheme.
    auto stage = [&](int n) {
        const int kn = n * 64;
        if (half == 0) {
            const int kc = (w7 >> 2) * 4 + lg;
            async16(Kp + (size_t)(kn + (w7 & 3) * 16 + lc) * DK_ + kc * 8,
                    &KV[n & 3][0][(w7 * 64 + lane) * 8]);
        } else {
            const int kcv = (w7 >> 2) * 4 + sg;
            async16(Vt + (size_t)((w7 & 3) * 16 + lc) * S_ + kn + kcv * 8,
                    &KV[n & 3][1][(w7 * 64 + lane) * 8]);
        }
    };

    stage(0); stage(1); stage(2);        // prologue: 3 loads in flight / wave

    for (int j = 0; j <= hi; ++j) {
        if (j + 2 <= hi)      asm volatile("s_waitcnt vmcnt(2)" ::: "memory");
        else if (j + 1 <= hi) asm volatile("s_waitcnt vmcnt(1)" ::: "memory");
        else                  asm volatile("s_waitcnt vmcnt(0)" ::: "memory");
        __builtin_amdgcn_s_barrier();    // raw barrier: no vmcnt drain
        if (j + 3 <= hi) stage(j + 3);   // overwrites buf (j-1)&3: safe

        if (j <= myq) {                  // lo waves stage-only past lo
            const bf16* ks = KV[j & 3][0];
            const bf16* vs = KV[j & 3][1];

            // k-split compute (r10-proven): this wave's k-half only
            bf16x8 kf0[2], kf1[2], vf[4];
            #pragma unroll
            for (int tt = 0; tt < 2; ++tt) {
                const int t = 2 * kh + tt;
                kf0[tt] = ldg8(&ks[(t * 64 + lane) * 8]);
                kf1[tt] = ldg8(&ks[(256 + t * 64 + lane) * 8]);
            }
            #pragma unroll
            for (int t = 0; t < 4; ++t)
                vf[t] = ldg8(&vs[(kh * 256 + t * 64 + lane) * 8]);

            f32x4 st[2];
            #pragma unroll
            for (int tt = 0; tt < 2; ++tt) {
                f32x4 zz = {};
                zz = MFMA16(kf0[tt], qf0, zz);
                st[tt] = MFMA16(kf1[tt], qf1, zz);
            }
            float rs = 0.f;
            if (j == myq) {              // diagonal tile: causal mask
                #pragma unroll
                for (int tt = 0; tt < 2; ++tt)
                    #pragma unroll
                    for (int r = 0; r < 4; ++r) {
                        const int kl = (2 * kh + tt) * 16 + lg * 4 + r;
                        const float pv = EXP2((kl <= mrow) ? st[tt][r] : -1e30f);
                        st[tt][r] = pv;
                        rs += pv;
                    }
            } else {
                #pragma unroll
                for (int tt = 0; tt < 2; ++tt)
                    #pragma unroll
                    for (int r = 0; r < 4; ++r) {
                        const float pv = EXP2(st[tt][r]);
                        st[tt][r] = pv;
                        rs += pv;
                    }
            }
            li += rs;

            const bf16x8 p = pfrag(st[0], st[1]);   // this k-half, sigma order

            #pragma unroll
            for (int t = 0; t < 4; ++t)
                accO[t] = MFMA16(vf[t], p, accO[t]);
        }
    }

    // ---- merge k-halves (once), then frag-major epilogue -------------------
    __syncthreads();                     // full drain; KV reusable
    float* scr = (float*)&KV[0][0][0];   // 8 pairs x 64 lanes x 17 f32 = 34.8KB
    const int slot = (half * 4 + wv) * 64 + lane;
    if (kh == 1) {
        float* s = scr + (size_t)slot * 17;
        #pragma unroll
        for (int t = 0; t < 4; ++t)
            #pragma unroll
            for (int r = 0; r < 4; ++r) s[t * 4 + r] = accO[t][r];
        s[16] = li;
    }
    __syncthreads();
    if (kh == 0) {
        const float* s = scr + (size_t)slot * 17;
        #pragma unroll
        for (int t = 0; t < 4; ++t)
            #pragma unroll
            for (int r = 0; r < 4; ++r) accO[t][r] += s[t * 4 + r];
        li += s[16];
        li += __shfl_xor(li, 16); li += __shfl_xor(li, 32);
        const float rl = 1.0f / li;
        // T buffers at byte offset 36864 (past scratch), 8 x 1280 bf16 = 20KB
        bf16* T = (bf16*)((char*)&KV[0][0][0] + 36864) + (half * 4 + wv) * 1280;

        #pragma unroll
        for (int t = 0; t < 4; ++t) {
            bf16x4 ov;
            #pragma unroll
            for (int r = 0; r < 4; ++r) ov[r] = (bf16)(accO[t][r] * rl);
            *reinterpret_cast<bf16x4*>(&T[lc * 72 + t * 16 + lg * 4]) = ov;
        }
        #pragma unroll
        for (int kk = 0; kk < 2; ++kk) {
            bf16x8 o8 = ldg8(&T[lc * 72 + kk * 32 + lg * 8]);
            *reinterpret_cast<bf16x8*>(
                &CtxF[fragbase(b * 32 + myq, h, kk, wv) + (size_t)lane * 8]) = o8;
        }
    }
}

extern "C" void kernel_launch(void* const* d_in, const int* in_sizes, int n_in,
                              void* d_out, int out_size, void* d_ws, size_t ws_size,
                              hipStream_t stream)
{
    float* out = (float*)d_out;

    bf16* Xf   = (bf16*)d_ws;                         // [3][M_*D_] frag-major
    bf16* Wf   = Xf + (size_t)3 * M_ * D_;            // [4][D_*D_] frag-major
    bf16* qkv  = Wf + (size_t)4 * D_ * D_;            // Q,K [bh][s][64]; V^T [bh][d][s]
    bf16* ctxF = qkv + (size_t)3 * M_ * D_;           // [M_*D_] frag-major

    cvt_all<<<6656, 256, 0, stream>>>(
        (const float*)d_in[0], (const float*)d_in[1], (const float*)d_in[2],
        (const float*)d_in[3], (const float*)d_in[4], (const float*)d_in[5],
        (const float*)d_in[6], Xf);

    gemm_qkv<<<dim3(768), 256, 0, stream>>>(Xf, Wf, qkv);
    attn<<<dim3(512), 1024, 0, stream>>>(qkv, ctxF);
    gemm_out<<<dim3(512), 256, 0, stream>>>(ctxF, Wf + (size_t)3 * D_ * D_, out);
}

// Round 12
// 170.032 us; speedup vs baseline: 1.1207x; 1.1207x over previous
//
#include <hip/hip_runtime.h>
#include <hip/hip_bf16.h>
#include <math.h>

#define B_  4
#define S_  2048
#define D_  512
#define H_  8
#define DK_ 64
#define M_  (B_ * S_)   // 8192

using bf16   = __bf16;
using bf16x4 = __bf16 __attribute__((ext_vector_type(4)));
using bf16x8 = __bf16 __attribute__((ext_vector_type(8)));
using f32x4  = float __attribute__((ext_vector_type(4)));

#define MFMA16(a, b, c) __builtin_amdgcn_mfma_f32_16x16x32_bf16((a), (b), (c), 0, 0, 0)
#define EXP2(x) exp2f(x)

typedef __attribute__((address_space(3))) void       lds_void;
typedef const __attribute__((address_space(1))) void gbl_void;

__device__ __forceinline__ void async16(const bf16* g, bf16* lds) {
    __builtin_amdgcn_global_load_lds((gbl_void*)g, (lds_void*)lds, 16, 0, 0);
}

__device__ __forceinline__ bf16x8 ldg8(const bf16* p) {
    return *reinterpret_cast<const bf16x8*>(p);
}

// Fragment-major layout for a [R x 512] matrix (rows = MFMA m/n dim, cols = K):
// chunk(g,k0,kk,t) holds rows g*64+t*16+{0..15}, cols k0*64+kk*32+{0..31};
// lane = (k_sub>>3)*16 + (row&15), 8 bf16 per lane.
__device__ __forceinline__ size_t fragbase(int g, int k0, int kk, int t) {
    return ((((size_t)(g * 8 + k0) * 2 + kk) * 4 + t) * 64) * 8;
}

// ---------------------------------------------------------------------------
// Fused f32->bf16 conversion + fragment-major re-layout (r5-proven form).
// ---------------------------------------------------------------------------
__global__ __launch_bounds__(256) void cvt_all(
    const float* __restrict__ x0, const float* __restrict__ x1, const float* __restrict__ x2,
    const float* __restrict__ w0, const float* __restrict__ w1,
    const float* __restrict__ w2, const float* __restrict__ w3,
    bf16* __restrict__ dst)
{
    const int w    = blockIdx.x * 4 + (threadIdx.x >> 6);  // wave id, 0..26623
    const int lane = threadIdx.x & 63;
    const int lg = lane >> 4, lc = lane & 15;
    const float* src;
    int c;
    size_t dbase;
    if (w < 24576) {                                       // X tensors: 3 x 8192 chunks
        const int seg = w >> 13;
        c = w & 8191;
        src = (seg == 0) ? x0 : (seg == 1) ? x1 : x2;
        dbase = (size_t)seg << 22;
    } else {                                               // W tensors: 4 x 512 chunks
        const int jj = w - 24576;
        const int seg = jj >> 9;
        c = jj & 511;
        src = (seg == 0) ? w0 : (seg == 1) ? w1 : (seg == 2) ? w2 : w3;
        dbase = ((size_t)3 << 22) + ((size_t)seg << 18);
    }
    const int g = c >> 6, k0 = (c >> 3) & 7, kk = (c >> 2) & 1, t = c & 3;
    const size_t soff = ((size_t)(g * 64 + t * 16 + lc) << 9) + k0 * 64 + kk * 32 + lg * 8;
    f32x4 a = *reinterpret_cast<const f32x4*>(src + soff);
    f32x4 b = *reinterpret_cast<const f32x4*>(src + soff + 4);
    bf16x8 r;
    #pragma unroll
    for (int j = 0; j < 4; ++j) { r[j] = (bf16)a[j]; r[j + 4] = (bf16)b[j]; }
    *reinterpret_cast<bf16x8*>(dst + dbase + ((size_t)c << 9) + (size_t)lane * 8) = r;
}

// ---------------------------------------------------------------------------
// QKV projection, LDS-FREE (r5-proven form). Grid 768; XCD-affine mt decode.
// ---------------------------------------------------------------------------
__global__ __launch_bounds__(256) void gemm_qkv(
    const bf16* __restrict__ Xf, const bf16* __restrict__ Wf,
    bf16* __restrict__ qkv)
{
    const int bx  = blockIdx.x;
    const int xcd = bx & 7;
    const int idx = bx >> 3;
    const int mt  = xcd + 8 * (idx & 7);       // 0..63: X 128-row tile
    const int rest = idx >> 3;
    const int nt  = rest & 3;                  // 0..3: W 128-row tile
    const int z   = rest >> 2;                 // 0..2

    const bf16* Xz = Xf + (size_t)z * M_ * D_;
    const bf16* Wz = Wf + (size_t)z * D_ * D_;
    const bool vz = (z == 2);
    const bf16* A  = vz ? Xz : Wz;
    const bf16* Bm = vz ? Wz : Xz;

    const int lane = threadIdx.x & 63;
    const int wave = threadIdx.x >> 6;
    const int lc = lane & 15;
    const int lg = lane >> 4;
    const int gA = (vz ? 2 * mt : 2 * nt) + (wave >> 1);
    const int gB = (vz ? 2 * nt : 2 * mt) + (wave & 1);

    f32x4 acc[4][4] = {};

    #pragma unroll
    for (int k0 = 0; k0 < 8; ++k0) {
        #pragma unroll
        for (int kk = 0; kk < 2; ++kk) {
            bf16x8 af[4], bfm[4];
            #pragma unroll
            for (int t = 0; t < 4; ++t)
                af[t] = ldg8(A + fragbase(gA, k0, kk, t) + (size_t)lane * 8);
            #pragma unroll
            for (int t = 0; t < 4; ++t)
                bfm[t] = ldg8(Bm + fragbase(gB, k0, kk, t) + (size_t)lane * 8);
            #pragma unroll
            for (int mi = 0; mi < 4; ++mi)
                #pragma unroll
                for (int ni = 0; ni < 4; ++ni)
                    acc[mi][ni] = MFMA16(af[mi], bfm[ni], acc[mi][ni]);
        }
    }

    if (z < 2) {
        bf16* Y = qkv + (size_t)z * M_ * D_;
        const float sc = (z == 0) ? 0.125f * 1.4426950408889634f : 1.0f;
        #pragma unroll
        for (int mi = 0; mi < 4; ++mi)
            #pragma unroll
            for (int ni = 0; ni < 4; ++ni) {
                const int d = gA * 64 + mi * 16 + lg * 4;
                const int s = gB * 64 + ni * 16 + lc;
                bf16x4 v;
                #pragma unroll
                for (int r = 0; r < 4; ++r) v[r] = (bf16)(acc[mi][ni][r] * sc);
                const size_t oidx =
                    ((((size_t)(s >> 11) * H_ + (d >> 6)) * S_
                      + (s & (S_ - 1))) << 6) + (d & 63);
                *reinterpret_cast<bf16x4*>(&Y[oidx]) = v;
            }
    } else {
        bf16* Y = qkv + (size_t)2 * M_ * D_;
        #pragma unroll
        for (int mi = 0; mi < 4; ++mi)
            #pragma unroll
            for (int ni = 0; ni < 4; ++ni) {
                const int s = gA * 64 + mi * 16 + lg * 4;
                const int d = gB * 64 + ni * 16 + lc;
                bf16x4 v;
                #pragma unroll
                for (int r = 0; r < 4; ++r) v[r] = (bf16)acc[mi][ni][r];
                const size_t oidx =
                    ((((size_t)(s >> 11)) * H_ + (d >> 6)) << 17)
                    + (size_t)(d & 63) * S_ + (s & (S_ - 1));
                *reinterpret_cast<bf16x4*>(&Y[oidx]) = v;
            }
    }
}

// ---------------------------------------------------------------------------
// Output projection, LDS-free (r5-proven form). Grid 512, XCD swizzle.
// ---------------------------------------------------------------------------
__global__ __launch_bounds__(256) void gemm_out(
    const bf16* __restrict__ CtxF, const bf16* __restrict__ WoF,
    float* __restrict__ out)
{
    const int bx  = blockIdx.x;
    const int xcd = bx & 7;
    const int idx = bx >> 3;
    const int mt  = xcd + 8 * (idx & 15);      // 0..127: ctx 64-row s-group
    const int nt  = idx >> 4;                  // 0..3: Wo 128-row d-tile

    const int lane = threadIdx.x & 63;
    const int wave = threadIdx.x >> 6;
    const int lc = lane & 15;
    const int lg = lane >> 4;
    const int gA = 2 * nt + (wave >> 1);       // Wo 64-row group
    const int tA = (wave & 1) * 2;             // 2 d-tiles per wave
    const int gB = mt;                         // ctx s-group

    f32x4 acc[2][4] = {};

    #pragma unroll
    for (int k0 = 0; k0 < 8; ++k0) {
        #pragma unroll
        for (int kk = 0; kk < 2; ++kk) {
            bf16x8 af[2], bfm[4];
            #pragma unroll
            for (int ai = 0; ai < 2; ++ai)
                af[ai] = ldg8(WoF + fragbase(gA, k0, kk, tA + ai) + (size_t)lane * 8);
            #pragma unroll
            for (int t = 0; t < 4; ++t)
                bfm[t] = ldg8(CtxF + fragbase(gB, k0, kk, t) + (size_t)lane * 8);
            #pragma unroll
            for (int ai = 0; ai < 2; ++ai)
                #pragma unroll
                for (int ni = 0; ni < 4; ++ni)
                    acc[ai][ni] = MFMA16(af[ai], bfm[ni], acc[ai][ni]);
        }
    }

    #pragma unroll
    for (int ai = 0; ai < 2; ++ai)
        #pragma unroll
        for (int ni = 0; ni < 4; ++ni) {
            const int d = gA * 64 + (tA + ai) * 16 + lg * 4;
            const int s = gB * 64 + ni * 16 + lc;
            *reinterpret_cast<f32x4*>(&out[(size_t)s * D_ + d]) = acc[ai][ni];
        }
}

// ---------------------------------------------------------------------------
// P->B-fragment in registers (permlane16_swap builtin; sigma-permuted V).
// ---------------------------------------------------------------------------
__device__ __forceinline__ bf16x8 pfrag(const f32x4 a, const f32x4 b) {
    union U4 { bf16x4 v; unsigned int u[2]; };
    U4 pa, pb;
    #pragma unroll
    for (int r = 0; r < 4; ++r) { pa.v[r] = (bf16)a[r]; pb.v[r] = (bf16)b[r]; }
    auto r0 = __builtin_amdgcn_permlane16_swap(pa.u[0], pb.u[0], false, false);
    auto r1 = __builtin_amdgcn_permlane16_swap(pa.u[1], pb.u[1], false, false);
    union U8 { unsigned int u[4]; bf16x8 v; } out;
    out.u[0] = r0[0]; out.u[1] = r1[0]; out.u[2] = r0[1]; out.u[3] = r1[1];
    return out.v;
}

// ---------------------------------------------------------------------------
// Causal flash attention, DUAL-TILE SHARED-FRAGMENT (r12).
// Model closed by r5/r10/r11: per-CU LDS traffic is INVARIANT under k-split
// (r5 16wv x 16rd == r11 32wv x 8rd == 256 b128/iter/CU) — each (q,kv)-tile
// pair costs 64 KB of LDS reads because fragments are re-read per q-tile.
// The only traffic-reducing lever: each wave holds BOTH paired q-tiles' Q in
// registers and uses one fragment read for two steps -> 32 KB/pair.
// Structure: r5 grid (512 blocks, anti-diagonal pair lo=pi/hi=31-pi, ONE
// round, 32 crit iters) x r10 compute (k-split, 8 ds_read_b128/wave/iter).
// Block 512 thr = 8 waves = 4 q-row-groups x 2 k-halves; per iter: step(hi)
// always, step(lo) while j<=lo. Per-CU bill: 16 waves x 8 = 128 b128 =
// 1536 cyc/iter (HALF of r5). Staging/ring-4/counted-vmcnt = r10 verbatim.
// k-half merge once at the end via LDS scratch; dual epilogue = r11 pattern.
// ---------------------------------------------------------------------------
__global__ __launch_bounds__(512, 4) void attn(
    const bf16* __restrict__ QKV, bf16* __restrict__ CtxF)
{
    const int bx = blockIdx.x;
    const int bh = (bx & 7) * 4 + ((bx >> 3) & 3);   // same-XCD bh grouping
    const int pi = bx >> 5;                           // 0..15
    const int b = bh >> 3, h = bh & 7;
    const size_t plane = (size_t)S_ * DK_;
    const bf16* Q  = QKV + (size_t)bh * plane;
    const bf16* Kp = QKV + (size_t)(B_ * H_) * plane + (size_t)bh * plane;
    const bf16* Vt = QKV + 2 * (size_t)(B_ * H_) * plane + (size_t)bh * plane;

    const int lane = threadIdx.x & 63;
    const int wave = threadIdx.x >> 6;   // 0..7
    const int wv   = wave >> 1;          // q row-group 0..3
    const int kh   = wave & 1;           // k-half
    const int lc = lane & 15;
    const int lg = lane >> 4;
    const int sg = ((lg & 1) << 1) | (lg >> 1);      // sigma(lg): swap 1<->2
    const int mrow = wv * 16 + lc;       // q row within tile for this lane

    __shared__ bf16 KV[4][2][64 * 64];   // ring-4 x {K,V}, 64 KB

    const int lo = pi;
    const int hi = 31 - pi;              // hi >= 16 always

    const int qH = hi * 64 + mrow;
    const int qL = lo * 64 + mrow;
    bf16x8 qfH0 = ldg8(Q + (size_t)qH * DK_ + lg * 8);
    bf16x8 qfH1 = ldg8(Q + (size_t)qH * DK_ + 32 + lg * 8);
    bf16x8 qfL0 = ldg8(Q + (size_t)qL * DK_ + lg * 8);
    bf16x8 qfL1 = ldg8(Q + (size_t)qL * DK_ + 32 + lg * 8);

    f32x4 accH[4] = {}, accL[4] = {};
    float liH = 0.f, liL = 0.f;

    // Staging (r10-proven): 1 K + 1 V async16 per wave per tile.
    const int srow = (wave & 3) * 16 + lc;
    const int kc   = (wave >> 2) * 4 + lg;           // K dk-chunk
    const int kcv  = (wave >> 2) * 4 + sg;           // sigma-permuted V chunk
    auto stage = [&](int n) {
        const int kn = n * 64;
        async16(Kp + (size_t)(kn + srow) * DK_ + kc * 8,
                &KV[n & 3][0][(wave * 64 + lane) * 8]);
        async16(Vt + (size_t)srow * S_ + kn + kcv * 8,
                &KV[n & 3][1][(wave * 64 + lane) * 8]);
    };

    stage(0); stage(1); stage(2);        // prologue: 6 loads in flight / wave

    for (int j = 0; j <= hi; ++j) {
        if (j + 2 <= hi)      asm volatile("s_waitcnt vmcnt(4)" ::: "memory");
        else if (j + 1 <= hi) asm volatile("s_waitcnt vmcnt(2)" ::: "memory");
        else                  asm volatile("s_waitcnt vmcnt(0)" ::: "memory");
        __builtin_amdgcn_s_barrier();    // raw barrier: no vmcnt drain
        if (j + 3 <= hi) stage(j + 3);   // overwrites buf (j-1)&3: safe

        const bf16* ks = KV[j & 3][0];
        const bf16* vs = KV[j & 3][1];

        // ONE fragment read, shared by both tiles (the r12 lever)
        bf16x8 kf0[2], kf1[2], vf[4];
        #pragma unroll
        for (int tt = 0; tt < 2; ++tt) {
            const int t = 2 * kh + tt;
            kf0[tt] = ldg8(&ks[(t * 64 + lane) * 8]);
            kf1[tt] = ldg8(&ks[(256 + t * 64 + lane) * 8]);
        }
        #pragma unroll
        for (int t = 0; t < 4; ++t)
            vf[t] = ldg8(&vs[(kh * 256 + t * 64 + lane) * 8]);

        auto step = [&](const bf16x8& qf0, const bf16x8& qf1, bool diag,
                        f32x4* accO, float& li) {
            f32x4 st[2];
            #pragma unroll
            for (int tt = 0; tt < 2; ++tt) {
                f32x4 zz = {};
                zz = MFMA16(kf0[tt], qf0, zz);
                st[tt] = MFMA16(kf1[tt], qf1, zz);
            }
            float rs = 0.f;
            if (diag) {
                #pragma unroll
                for (int tt = 0; tt < 2; ++tt)
                    #pragma unroll
                    for (int r = 0; r < 4; ++r) {
                        const int kl = (2 * kh + tt) * 16 + lg * 4 + r;
                        const float pv = EXP2((kl <= mrow) ? st[tt][r] : -1e30f);
                        st[tt][r] = pv;
                        rs += pv;
                    }
            } else {
                #pragma unroll
                for (int tt = 0; tt < 2; ++tt)
                    #pragma unroll
                    for (int r = 0; r < 4; ++r) {
                        const float pv = EXP2(st[tt][r]);
                        st[tt][r] = pv;
                        rs += pv;
                    }
            }
            li += rs;
            const bf16x8 p = pfrag(st[0], st[1]);   // this k-half, sigma order
            #pragma unroll
            for (int t = 0; t < 4; ++t)
                accO[t] = MFMA16(vf[t], p, accO[t]);
        };

        step(qfH0, qfH1, j == hi, accH, liH);
        if (j <= lo) step(qfL0, qfL1, j == lo, accL, liL);
    }

    // ---- merge k-halves (once, both tiles), then dual epilogue -------------
    __syncthreads();                     // full drain; KV reusable
    float* scr = (float*)&KV[0][0][0];   // 2 tiles x 4 wv x 64 lanes x 17 f32
    if (kh == 1) {
        #pragma unroll
        for (int tile = 0; tile < 2; ++tile) {
            const f32x4* accO = tile ? accL : accH;
            float* s = scr + (size_t)((tile * 4 + wv) * 64 + lane) * 17;
            #pragma unroll
            for (int t = 0; t < 4; ++t)
                #pragma unroll
                for (int r = 0; r < 4; ++r) s[t * 4 + r] = accO[t][r];
            s[16] = tile ? liL : liH;
        }
    }
    __syncthreads();
    if (kh == 0) {
        #pragma unroll
        for (int tile = 0; tile < 2; ++tile) {
            f32x4* accO = tile ? accL : accH;
            float li = tile ? liL : liH;
            const float* s = scr + (size_t)((tile * 4 + wv) * 64 + lane) * 17;
            #pragma unroll
            for (int t = 0; t < 4; ++t)
                #pragma unroll
                for (int r = 0; r < 4; ++r) accO[t][r] += s[t * 4 + r];
            li += s[16];
            li += __shfl_xor(li, 16); li += __shfl_xor(li, 32);
            const float rl = 1.0f / li;
            // T buffers at byte offset 36864 (past scratch): 8 x 1280 bf16
            bf16* T = (bf16*)((char*)&KV[0][0][0] + 36864)
                      + (tile * 4 + wv) * 1280;
            #pragma unroll
            for (int t = 0; t < 4; ++t) {
                bf16x4 ov;
                #pragma unroll
                for (int r = 0; r < 4; ++r) ov[r] = (bf16)(accO[t][r] * rl);
                *reinterpret_cast<bf16x4*>(&T[lc * 72 + t * 16 + lg * 4]) = ov;
            }
            const int jq = tile ? lo : hi;
            #pragma unroll
            for (int kk = 0; kk < 2; ++kk) {
                bf16x8 o8 = ldg8(&T[lc * 72 + kk * 32 + lg * 8]);
                *reinterpret_cast<bf16x8*>(
                    &CtxF[fragbase(b * 32 + jq, h, kk, wv) + (size_t)lane * 8]) = o8;
            }
        }
    }
}

extern "C" void kernel_launch(void* const* d_in, const int* in_sizes, int n_in,
                              void* d_out, int out_size, void* d_ws, size_t ws_size,
                              hipStream_t stream)
{
    float* out = (float*)d_out;

    bf16* Xf   = (bf16*)d_ws;                         // [3][M_*D_] frag-major
    bf16* Wf   = Xf + (size_t)3 * M_ * D_;            // [4][D_*D_] frag-major
    bf16* qkv  = Wf + (size_t)4 * D_ * D_;            // Q,K [bh][s][64]; V^T [bh][d][s]
    bf16* ctxF = qkv + (size_t)3 * M_ * D_;           // [M_*D_] frag-major

    cvt_all<<<6656, 256, 0, stream>>>(
        (const float*)d_in[0], (const float*)d_in[1], (const float*)d_in[2],
        (const float*)d_in[3], (const float*)d_in[4], (const float*)d_in[5],
        (const float*)d_in[6], Xf);

    gemm_qkv<<<dim3(768), 256, 0, stream>>>(Xf, Wf, qkv);
    attn<<<dim3(512), 512, 0, stream>>>(qkv, ctxF);
    gemm_out<<<dim3(512), 256, 0, stream>>>(ctxF, Wf + (size_t)3 * D_ * D_, out);
}